// Round 2
// baseline (438.107 us; speedup 1.0000x reference)
//
#include <hip/hip_runtime.h>

typedef unsigned short u16;
typedef __attribute__((ext_vector_type(8))) short bf16x8;  // 8 bf16 (4 VGPRs)
typedef __attribute__((ext_vector_type(4))) float f32x4;   // MFMA C/D frag

__device__ __forceinline__ float bf2f(u16 x) {
  union { unsigned u; float f; } v; v.u = ((unsigned)x) << 16; return v.f;
}
__device__ __forceinline__ u16 f2bf(float f) {
  union { float f; unsigned u; } v; v.f = f;
  unsigned r = v.u + 0x7FFFu + ((v.u >> 16) & 1u);  // RNE
  return (u16)(r >> 16);
}
__device__ __forceinline__ float clampf(float v) {
  return fmaxf(fminf(v, 1.0e4f), -1.0e4f);
}
// async global->LDS, 16B per lane; LDS dest = wave-uniform base + lane*16
__device__ __forceinline__ void gll16(const u16* g, u16* l) {
  __builtin_amdgcn_global_load_lds(
      (const __attribute__((address_space(1))) void*)g,
      (__attribute__((address_space(3))) void*)l, 16, 0, 0);
}

// ---------- convert x (f32) -> bf16 ----------
__global__ __launch_bounds__(256) void convert_x(
    const float* __restrict__ x, u16* __restrict__ xbf) {
  const int i0 = (blockIdx.x * 256 + threadIdx.x) * 4;
  const float4 v = *(const float4*)(x + i0);
  xbf[i0 + 0] = f2bf(v.x); xbf[i0 + 1] = f2bf(v.y);
  xbf[i0 + 2] = f2bf(v.z); xbf[i0 + 3] = f2bf(v.w);
}

// ---------- transpose f32 in[R][C] -> bf16 out[C][R] ----------
__global__ __launch_bounds__(256) void transpose_f32_bf16(
    const float* __restrict__ in, u16* __restrict__ out, int R, int C) {
  __shared__ u16 tile[32][33];
  const int bc = blockIdx.x * 32, br = blockIdx.y * 32;
  const int tx = threadIdx.x & 31, ty = threadIdx.x >> 5;
  #pragma unroll
  for (int i = ty; i < 32; i += 8)
    tile[i][tx] = f2bf(in[(size_t)(br + i) * C + bc + tx]);
  __syncthreads();
  #pragma unroll
  for (int i = ty; i < 32; i += 8)
    out[(size_t)(bc + i) * R + br + tx] = tile[tx][i];
}

// ---------- GEMM1: QKV projection, BK=64 dual 32-col LDS (FROZEN R14) ----------
__global__ __launch_bounds__(256) void gemm1_qkv(
    const u16* __restrict__ A, const u16* __restrict__ Bt,
    const float* __restrict__ bias, u16* __restrict__ qk,
    u16* __restrict__ vt, int K) {
  __shared__ u16 As0[128 * 32], As1[128 * 32];
  __shared__ u16 Bs0[128 * 32], Bs1[128 * 32];
  const int tid = threadIdx.x;
  const int m0 = blockIdx.x * 128, n0 = blockIdx.y * 128;
  const int wave = tid >> 6, lane = tid & 63;
  const int quad = lane >> 4, l16 = lane & 15;
  const int wm = (wave >> 1) * 64, wn = (wave & 1) * 64;
  const int sr = (lane >> 2), sp = lane & 3;

  f32x4 acc[4][4] = {};
  const u16* gA = A + (size_t)(m0 + wave * 32 + sr) * K + sp * 8;
  const u16* gB = Bt + (size_t)(n0 + wave * 32 + sr) * K + sp * 8;

  for (int k0 = 0; k0 < K; k0 += 64) {
    #pragma unroll
    for (int t = 0; t < 2; ++t) {
      gll16(gA + (size_t)(t * 16) * K + k0,      &As0[(wave * 32 + t * 16) * 32]);
      gll16(gA + (size_t)(t * 16) * K + k0 + 32, &As1[(wave * 32 + t * 16) * 32]);
      gll16(gB + (size_t)(t * 16) * K + k0,      &Bs0[(wave * 32 + t * 16) * 32]);
      gll16(gB + (size_t)(t * 16) * K + k0 + 32, &Bs1[(wave * 32 + t * 16) * 32]);
    }
    __syncthreads();
    #pragma unroll
    for (int ks = 0; ks < 2; ++ks) {
      const u16* Ah = ks ? As1 : As0;
      const u16* Bh = ks ? Bs1 : Bs0;
      bf16x8 af[4], bfr[4];
      #pragma unroll
      for (int i = 0; i < 4; ++i)
        af[i] = *(const bf16x8*)&Ah[(wm + i * 16 + l16) * 32 + quad * 8];
      #pragma unroll
      for (int j = 0; j < 4; ++j)
        bfr[j] = *(const bf16x8*)&Bh[(wn + j * 16 + l16) * 32 + quad * 8];
      #pragma unroll
      for (int i = 0; i < 4; ++i)
        #pragma unroll
        for (int j = 0; j < 4; ++j)
          acc[i][j] = __builtin_amdgcn_mfma_f32_16x16x32_bf16(af[i], bfr[j], acc[i][j], 0, 0, 0);
    }
    __syncthreads();
  }

  #pragma unroll
  for (int i = 0; i < 4; ++i) {
    const int row = m0 + wm + i * 16 + quad * 4;
    #pragma unroll
    for (int j = 0; j < 4; ++j) {
      const int col = n0 + wn + j * 16 + l16;
      const float bv = bias[col];
      if (col < 2048) {
        #pragma unroll
        for (int r = 0; r < 4; ++r)
          qk[(size_t)(row + r) * 2048 + col] = f2bf(clampf(acc[i][j][r] + bv));
      } else {
        const int d = col & 63;
        const int hh = (col - 2048) >> 6;
        #pragma unroll
        for (int r = 0; r < 4; ++r) {
          const int rr = row + r;
          const int bb = rr >> 11, ss = rr & 2047;
          vt[(size_t)(bb * 16 + hh) * 131072 + d * 2048 + ss] =
              f2bf(clampf(acc[i][j][r] + bv));
        }
      }
    }
  }
}

// ---------- GEMM2: out(f32) = ctx * w_proj^T + bias (FROZEN R14) ----------
__global__ __launch_bounds__(256) void gemm2_proj(
    const u16* __restrict__ A, const u16* __restrict__ Bt,
    const float* __restrict__ bias, float* __restrict__ out, int K) {
  __shared__ u16 As0[128 * 32], As1[128 * 32];
  __shared__ u16 Bs0[128 * 32], Bs1[128 * 32];
  const int tid = threadIdx.x;
  const int m0 = blockIdx.x * 128, n0 = blockIdx.y * 128;
  const int wave = tid >> 6, lane = tid & 63;
  const int quad = lane >> 4, l16 = lane & 15;
  const int wm = (wave >> 1) * 64, wn = (wave & 1) * 64;
  const int sr = (lane >> 2), sp = lane & 3;

  f32x4 acc[4][4] = {};
  const u16* gA = A + (size_t)(m0 + wave * 32 + sr) * K + sp * 8;
  const u16* gB = Bt + (size_t)(n0 + wave * 32 + sr) * K + sp * 8;

  for (int k0 = 0; k0 < K; k0 += 64) {
    #pragma unroll
    for (int t = 0; t < 2; ++t) {
      gll16(gA + (size_t)(t * 16) * K + k0,      &As0[(wave * 32 + t * 16) * 32]);
      gll16(gA + (size_t)(t * 16) * K + k0 + 32, &As1[(wave * 32 + t * 16) * 32]);
      gll16(gB + (size_t)(t * 16) * K + k0,      &Bs0[(wave * 32 + t * 16) * 32]);
      gll16(gB + (size_t)(t * 16) * K + k0 + 32, &Bs1[(wave * 32 + t * 16) * 32]);
    }
    __syncthreads();
    #pragma unroll
    for (int ks = 0; ks < 2; ++ks) {
      const u16* Ah = ks ? As1 : As0;
      const u16* Bh = ks ? Bs1 : Bs0;
      bf16x8 af[4], bfr[4];
      #pragma unroll
      for (int i = 0; i < 4; ++i)
        af[i] = *(const bf16x8*)&Ah[(wm + i * 16 + l16) * 32 + quad * 8];
      #pragma unroll
      for (int j = 0; j < 4; ++j)
        bfr[j] = *(const bf16x8*)&Bh[(wn + j * 16 + l16) * 32 + quad * 8];
      #pragma unroll
      for (int i = 0; i < 4; ++i)
        #pragma unroll
        for (int j = 0; j < 4; ++j)
          acc[i][j] = __builtin_amdgcn_mfma_f32_16x16x32_bf16(af[i], bfr[j], acc[i][j], 0, 0, 0);
    }
    __syncthreads();
  }

  #pragma unroll
  for (int i = 0; i < 4; ++i) {
    const int row = m0 + wm + i * 16 + quad * 4;
    #pragma unroll
    for (int j = 0; j < 4; ++j) {
      const int col = n0 + wn + j * 16 + l16;
      const float bv = bias[col];
      #pragma unroll
      for (int r = 0; r < 4; ++r)
        out[(size_t)(row + r) * 1024 + col] = clampf(acc[i][j][r] + bv);
    }
  }
}

// ---------- fused flash attention, v9 ----------
// Post-mortem v8: swizzle worked exactly as designed (conflicts 10.5M -> 0)
// but 256-row blocks cut the grid to 512 = 2 blocks/CU; occupancy 33% -> 21%
// and ALL pipes idled (MFMA 29->21, VALU 36->27): latency-bound. Lesson:
// waves/CU dominates LDS-byte savings here.
// v9 = v7 geometry (128-row blocks, 32 q-rows/wave, grid (64,16) = 4
// blocks/CU, 16 waves/CU) + v8's proven zero-conflict compact tiles:
// [64][64] with 16B-block XOR swizzle key=(row^(row>>2))&7 (bijective per
// row, b128 stays 16B-aligned, scalar Pl writes spread over all 32 banks).
// LDS 36.8KB -> 32KB. Expect v7's 113us minus the ~41k conflict
// cycles/CU => ~95us, conflicts ~0.
__device__ __forceinline__ int swz(int row, int col) {
  const int key = (row ^ (row >> 2)) & 7;
  return row * 64 + (((col >> 3) ^ key) << 3) + (col & 7);
}

__global__ __launch_bounds__(256, 4) void attn_fused(
    const u16* __restrict__ qk, const u16* __restrict__ vt,
    u16* __restrict__ ctx) {
  __shared__ u16 Ks[64 * 64];
  __shared__ u16 Vs[64 * 64];
  __shared__ u16 Pl[4 * 32 * 64];
  const int bh = blockIdx.x, qt = blockIdx.y;
  const int b = bh >> 4, h = bh & 15;
  const int tid = threadIdx.x;
  const int w = tid >> 6, lane = tid & 63;
  const int quad = lane >> 4, l16 = lane & 15;
  const int qbase = qt * 128 + w * 32;

  const u16* qptr = qk + (size_t)(b * 2048) * 2048 + h * 64;
  bf16x8 qf[2][2];
  #pragma unroll
  for (int i = 0; i < 2; ++i)
    #pragma unroll
    for (int ks = 0; ks < 2; ++ks)
      qf[i][ks] = *(const bf16x8*)(qptr + (size_t)(qbase + i * 16 + l16) * 2048 + ks * 32 + quad * 8);

  const u16* kptr = qk + (size_t)(b * 2048) * 2048 + 1024 + h * 64;
  const u16* vptr = vt + (size_t)bh * 131072;

  const int srow = tid >> 3, scol = (tid & 7) * 8;
  u16* Pw = Pl + w * 2048;

  f32x4 o[2][4] = {};
  f32x4 lacc[2] = {};
  const short one = (short)0x3F80;  // bf16 1.0
  const bf16x8 ones = {one, one, one, one, one, one, one, one};
  const float c2 = 0.125f * 1.44269504088896340736f;

  bf16x8 k0 = *(const bf16x8*)(kptr + (size_t)srow * 2048 + scol);
  bf16x8 k1 = *(const bf16x8*)(kptr + (size_t)(srow + 32) * 2048 + scol);
  bf16x8 v0 = *(const bf16x8*)(vptr + (size_t)srow * 2048 + scol);
  bf16x8 v1 = *(const bf16x8*)(vptr + (size_t)(srow + 32) * 2048 + scol);

  for (int kv0 = 0; kv0 < 2048; kv0 += 64) {
    __syncthreads();
    *(bf16x8*)&Ks[swz(srow, scol)]      = k0;
    *(bf16x8*)&Ks[swz(srow + 32, scol)] = k1;
    *(bf16x8*)&Vs[swz(srow, scol)]      = v0;
    *(bf16x8*)&Vs[swz(srow + 32, scol)] = v1;
    __syncthreads();
    const int kvn = (kv0 + 64) & 2047;
    k0 = *(const bf16x8*)(kptr + (size_t)(kvn + srow) * 2048 + scol);
    k1 = *(const bf16x8*)(kptr + (size_t)(kvn + srow + 32) * 2048 + scol);
    v0 = *(const bf16x8*)(vptr + (size_t)srow * 2048 + kvn + scol);
    v1 = *(const bf16x8*)(vptr + (size_t)(srow + 32) * 2048 + kvn + scol);

    f32x4 s[2][4] = {};
    #pragma unroll
    for (int jj = 0; jj < 4; ++jj) {
      #pragma unroll
      for (int ks = 0; ks < 2; ++ks) {
        bf16x8 kf = *(const bf16x8*)&Ks[swz(jj * 16 + l16, ks * 32 + quad * 8)];
        #pragma unroll
        for (int i = 0; i < 2; ++i)
          s[i][jj] = __builtin_amdgcn_mfma_f32_16x16x32_bf16(qf[i][ks], kf, s[i][jj], 0, 0, 0);
      }
    }
    #pragma unroll
    for (int i = 0; i < 2; ++i)
      #pragma unroll
      for (int jj = 0; jj < 4; ++jj)
        #pragma unroll
        for (int r = 0; r < 4; ++r) {
          const float p = __builtin_amdgcn_exp2f(s[i][jj][r] * c2);  // bare v_exp_f32
          union { float f; unsigned u; } vv; vv.f = p;
          Pw[swz(i * 16 + quad * 4 + r, jj * 16 + l16)] = (u16)((vv.u + 0x8000u) >> 16);
        }
    #pragma unroll
    for (int ks = 0; ks < 2; ++ks) {
      bf16x8 af0 = *(const bf16x8*)&Pw[swz(l16, ks * 32 + quad * 8)];
      bf16x8 af1 = *(const bf16x8*)&Pw[swz(16 + l16, ks * 32 + quad * 8)];
      lacc[0] = __builtin_amdgcn_mfma_f32_16x16x32_bf16(af0, ones, lacc[0], 0, 0, 0);
      lacc[1] = __builtin_amdgcn_mfma_f32_16x16x32_bf16(af1, ones, lacc[1], 0, 0, 0);
      #pragma unroll
      for (int j = 0; j < 4; ++j) {
        bf16x8 vf = *(const bf16x8*)&Vs[swz(j * 16 + l16, ks * 32 + quad * 8)];
        o[0][j] = __builtin_amdgcn_mfma_f32_16x16x32_bf16(af0, vf, o[0][j], 0, 0, 0);
        o[1][j] = __builtin_amdgcn_mfma_f32_16x16x32_bf16(af1, vf, o[1][j], 0, 0, 0);
      }
    }
  }

  u16* cbase = ctx + (size_t)(b * 2048) * 1024 + h * 64;
  #pragma unroll
  for (int i = 0; i < 2; ++i)
    #pragma unroll
    for (int r = 0; r < 4; ++r) {
      const float inv = 1.0f / lacc[i][r];
      const int q = qbase + i * 16 + quad * 4 + r;
      #pragma unroll
      for (int j = 0; j < 4; ++j)
        cbase[(size_t)q * 1024 + j * 16 + l16] = f2bf(o[i][j][r] * inv);
    }
}

extern "C" void kernel_launch(void* const* d_in, const int* in_sizes, int n_in,
                              void* d_out, int out_size, void* d_ws, size_t ws_size,
                              hipStream_t stream) {
  (void)out_size;
  const float *x = nullptr, *wq = nullptr, *bq = nullptr, *wp = nullptr, *bp = nullptr;
  for (int i = 0; i < n_in; ++i) {
    switch (in_sizes[i]) {
      case 8388608: x  = (const float*)d_in[i]; break;
      case 3145728: wq = (const float*)d_in[i]; break;
      case 3072:    bq = (const float*)d_in[i]; break;
      case 1048576: wp = (const float*)d_in[i]; break;
      case 1024:    bp = (const float*)d_in[i]; break;
      default: break;
    }
  }
  if (!x || !wq || !bq || !wp || !bp) {
    x  = (const float*)d_in[0]; wq = (const float*)d_in[1];
    bq = (const float*)d_in[2]; wp = (const float*)d_in[3];
    bp = (const float*)d_in[4];
  }
  float* out = (float*)d_out;

  const size_t NEED = 75497472;
  if (ws_size < NEED) return;

  char* ws = (char*)d_ws;
  u16* qkb = (u16*)(ws);              // [8192][2048] Q,K
  u16* vt  = (u16*)(ws + 33554432);   // [64][64][2048] V^T
  u16* xbf = (u16*)(ws + 50331648);   // x_bf, then ctx
  u16* wT1 = (u16*)(ws + 67108864);
  u16* wT2 = (u16*)(ws + 73400320);

  convert_x<<<8192, 256, 0, stream>>>(x, xbf);
  transpose_f32_bf16<<<dim3(96, 32), 256, 0, stream>>>(wq, wT1, 1024, 3072);
  transpose_f32_bf16<<<dim3(32, 32), 256, 0, stream>>>(wp, wT2, 1024, 1024);
  gemm1_qkv<<<dim3(64, 24), 256, 0, stream>>>(xbf, wT1, bq, qkb, vt, 1024);
  attn_fused<<<dim3(64, 16), 256, 0, stream>>>(qkb, vt, xbf /*ctx*/);
  gemm2_proj<<<dim3(64, 8), 256, 0, stream>>>(xbf /*ctx*/, wT2, bp, out, 1024);
}

// Round 3
// 290.099 us; speedup vs baseline: 1.5102x; 1.5102x over previous
//
#include <hip/hip_runtime.h>

typedef unsigned short u16;
typedef __attribute__((ext_vector_type(8))) short bf16x8;  // 8 bf16 (4 VGPRs)
typedef __attribute__((ext_vector_type(4))) float f32x4;   // MFMA C/D frag

__device__ __forceinline__ float bf2f(u16 x) {
  union { unsigned u; float f; } v; v.u = ((unsigned)x) << 16; return v.f;
}
__device__ __forceinline__ u16 f2bf(float f) {
  union { float f; unsigned u; } v; v.f = f;
  unsigned r = v.u + 0x7FFFu + ((v.u >> 16) & 1u);  // RNE
  return (u16)(r >> 16);
}
__device__ __forceinline__ float clampf(float v) {
  return fmaxf(fminf(v, 1.0e4f), -1.0e4f);
}
// async global->LDS, 16B per lane; LDS dest = wave-uniform base + lane*16
__device__ __forceinline__ void gll16(const u16* g, u16* l) {
  __builtin_amdgcn_global_load_lds(
      (const __attribute__((address_space(1))) void*)g,
      (__attribute__((address_space(3))) void*)l, 16, 0, 0);
}

// ---------- convert x (f32) -> bf16 ----------
__global__ __launch_bounds__(256) void convert_x(
    const float* __restrict__ x, u16* __restrict__ xbf) {
  const int i0 = (blockIdx.x * 256 + threadIdx.x) * 4;
  const float4 v = *(const float4*)(x + i0);
  xbf[i0 + 0] = f2bf(v.x); xbf[i0 + 1] = f2bf(v.y);
  xbf[i0 + 2] = f2bf(v.z); xbf[i0 + 3] = f2bf(v.w);
}

// ---------- transpose f32 in[R][C] -> bf16 out[C][R] ----------
__global__ __launch_bounds__(256) void transpose_f32_bf16(
    const float* __restrict__ in, u16* __restrict__ out, int R, int C) {
  __shared__ u16 tile[32][33];
  const int bc = blockIdx.x * 32, br = blockIdx.y * 32;
  const int tx = threadIdx.x & 31, ty = threadIdx.x >> 5;
  #pragma unroll
  for (int i = ty; i < 32; i += 8)
    tile[i][tx] = f2bf(in[(size_t)(br + i) * C + bc + tx]);
  __syncthreads();
  #pragma unroll
  for (int i = ty; i < 32; i += 8)
    out[(size_t)(bc + i) * R + br + tx] = tile[tx][i];
}

// ---------- GEMM1: QKV projection, BK=64 dual 32-col LDS (FROZEN R14) ----------
__global__ __launch_bounds__(256) void gemm1_qkv(
    const u16* __restrict__ A, const u16* __restrict__ Bt,
    const float* __restrict__ bias, u16* __restrict__ qk,
    u16* __restrict__ vt, int K) {
  __shared__ u16 As0[128 * 32], As1[128 * 32];
  __shared__ u16 Bs0[128 * 32], Bs1[128 * 32];
  const int tid = threadIdx.x;
  const int m0 = blockIdx.x * 128, n0 = blockIdx.y * 128;
  const int wave = tid >> 6, lane = tid & 63;
  const int quad = lane >> 4, l16 = lane & 15;
  const int wm = (wave >> 1) * 64, wn = (wave & 1) * 64;
  const int sr = (lane >> 2), sp = lane & 3;

  f32x4 acc[4][4] = {};
  const u16* gA = A + (size_t)(m0 + wave * 32 + sr) * K + sp * 8;
  const u16* gB = Bt + (size_t)(n0 + wave * 32 + sr) * K + sp * 8;

  for (int k0 = 0; k0 < K; k0 += 64) {
    #pragma unroll
    for (int t = 0; t < 2; ++t) {
      gll16(gA + (size_t)(t * 16) * K + k0,      &As0[(wave * 32 + t * 16) * 32]);
      gll16(gA + (size_t)(t * 16) * K + k0 + 32, &As1[(wave * 32 + t * 16) * 32]);
      gll16(gB + (size_t)(t * 16) * K + k0,      &Bs0[(wave * 32 + t * 16) * 32]);
      gll16(gB + (size_t)(t * 16) * K + k0 + 32, &Bs1[(wave * 32 + t * 16) * 32]);
    }
    __syncthreads();
    #pragma unroll
    for (int ks = 0; ks < 2; ++ks) {
      const u16* Ah = ks ? As1 : As0;
      const u16* Bh = ks ? Bs1 : Bs0;
      bf16x8 af[4], bfr[4];
      #pragma unroll
      for (int i = 0; i < 4; ++i)
        af[i] = *(const bf16x8*)&Ah[(wm + i * 16 + l16) * 32 + quad * 8];
      #pragma unroll
      for (int j = 0; j < 4; ++j)
        bfr[j] = *(const bf16x8*)&Bh[(wn + j * 16 + l16) * 32 + quad * 8];
      #pragma unroll
      for (int i = 0; i < 4; ++i)
        #pragma unroll
        for (int j = 0; j < 4; ++j)
          acc[i][j] = __builtin_amdgcn_mfma_f32_16x16x32_bf16(af[i], bfr[j], acc[i][j], 0, 0, 0);
    }
    __syncthreads();
  }

  #pragma unroll
  for (int i = 0; i < 4; ++i) {
    const int row = m0 + wm + i * 16 + quad * 4;
    #pragma unroll
    for (int j = 0; j < 4; ++j) {
      const int col = n0 + wn + j * 16 + l16;
      const float bv = bias[col];
      if (col < 2048) {
        #pragma unroll
        for (int r = 0; r < 4; ++r)
          qk[(size_t)(row + r) * 2048 + col] = f2bf(clampf(acc[i][j][r] + bv));
      } else {
        const int d = col & 63;
        const int hh = (col - 2048) >> 6;
        #pragma unroll
        for (int r = 0; r < 4; ++r) {
          const int rr = row + r;
          const int bb = rr >> 11, ss = rr & 2047;
          vt[(size_t)(bb * 16 + hh) * 131072 + d * 2048 + ss] =
              f2bf(clampf(acc[i][j][r] + bv));
        }
      }
    }
  }
}

// ---------- GEMM2: out(f32) = ctx * w_proj^T + bias (FROZEN R14) ----------
__global__ __launch_bounds__(256) void gemm2_proj(
    const u16* __restrict__ A, const u16* __restrict__ Bt,
    const float* __restrict__ bias, float* __restrict__ out, int K) {
  __shared__ u16 As0[128 * 32], As1[128 * 32];
  __shared__ u16 Bs0[128 * 32], Bs1[128 * 32];
  const int tid = threadIdx.x;
  const int m0 = blockIdx.x * 128, n0 = blockIdx.y * 128;
  const int wave = tid >> 6, lane = tid & 63;
  const int quad = lane >> 4, l16 = lane & 15;
  const int wm = (wave >> 1) * 64, wn = (wave & 1) * 64;
  const int sr = (lane >> 2), sp = lane & 3;

  f32x4 acc[4][4] = {};
  const u16* gA = A + (size_t)(m0 + wave * 32 + sr) * K + sp * 8;
  const u16* gB = Bt + (size_t)(n0 + wave * 32 + sr) * K + sp * 8;

  for (int k0 = 0; k0 < K; k0 += 64) {
    #pragma unroll
    for (int t = 0; t < 2; ++t) {
      gll16(gA + (size_t)(t * 16) * K + k0,      &As0[(wave * 32 + t * 16) * 32]);
      gll16(gA + (size_t)(t * 16) * K + k0 + 32, &As1[(wave * 32 + t * 16) * 32]);
      gll16(gB + (size_t)(t * 16) * K + k0,      &Bs0[(wave * 32 + t * 16) * 32]);
      gll16(gB + (size_t)(t * 16) * K + k0 + 32, &Bs1[(wave * 32 + t * 16) * 32]);
    }
    __syncthreads();
    #pragma unroll
    for (int ks = 0; ks < 2; ++ks) {
      const u16* Ah = ks ? As1 : As0;
      const u16* Bh = ks ? Bs1 : Bs0;
      bf16x8 af[4], bfr[4];
      #pragma unroll
      for (int i = 0; i < 4; ++i)
        af[i] = *(const bf16x8*)&Ah[(wm + i * 16 + l16) * 32 + quad * 8];
      #pragma unroll
      for (int j = 0; j < 4; ++j)
        bfr[j] = *(const bf16x8*)&Bh[(wn + j * 16 + l16) * 32 + quad * 8];
      #pragma unroll
      for (int i = 0; i < 4; ++i)
        #pragma unroll
        for (int j = 0; j < 4; ++j)
          acc[i][j] = __builtin_amdgcn_mfma_f32_16x16x32_bf16(af[i], bfr[j], acc[i][j], 0, 0, 0);
    }
    __syncthreads();
  }

  #pragma unroll
  for (int i = 0; i < 4; ++i) {
    const int row = m0 + wm + i * 16 + quad * 4;
    #pragma unroll
    for (int j = 0; j < 4; ++j) {
      const int col = n0 + wn + j * 16 + l16;
      const float bv = bias[col];
      #pragma unroll
      for (int r = 0; r < 4; ++r)
        out[(size_t)(row + r) * 1024 + col] = clampf(acc[i][j][r] + bv);
    }
  }
}

// ---------- fused flash attention, v10 ----------
// Post-mortem v8/v9: any change to the K/V tile geometry or LDS footprint
// that moves blocks/CU off exactly 4 wrecks the schedule. v9 (32KB tiles,
// 5 blocks/CU possible) -> uneven packing -> same-bh cohorts drift ->
// FETCH_SIZE 38.5MB -> 200MB (K/V L2 re-fetch) -> 255us. v8 (48KB, 2-3
// blocks/CU) -> latency-bound -> 150us. v7 (36.8KB = exactly 4 blocks/CU,
// all 1024 blocks resident, lockstep) = 113us.
// v10 = v7 byte-identical EXCEPT Pl row stride 72 -> 68 u16.
//   Pl scalar-write bank = (34*row + (col>>1)) & 31. Stride 72: 4*quad rows
//   -> 16*quad (mod 32) -> quads alias in pairs -> 16 banks, 4 lanes/bank
//   = the measured 10.49M conflict cycles. Stride 68: 8*quad -> {0,8,16,24}
//   -> 32 banks, 2 lanes/bank (even/odd l16 share a dword) = free [m136].
//   Pl b128 reads at stride 68: phase start 2*l16+4*quad -> 2-way = free.
//   K/V stay at stride 72 (known good). LDS 36864 -> 35840B, still exactly
//   4 blocks/CU.
__global__ __launch_bounds__(256, 4) void attn_fused(
    const u16* __restrict__ qk, const u16* __restrict__ vt,
    u16* __restrict__ ctx) {
  __shared__ u16 Ks[64][72];
  __shared__ u16 Vs[64][72];
  __shared__ u16 Pl[4][32][68];
  const int bh = blockIdx.x, qt = blockIdx.y;
  const int b = bh >> 4, h = bh & 15;
  const int tid = threadIdx.x;
  const int w = tid >> 6, lane = tid & 63;
  const int quad = lane >> 4, l16 = lane & 15;
  const int qbase = qt * 128 + w * 32;

  const u16* qptr = qk + (size_t)(b * 2048) * 2048 + h * 64;
  bf16x8 qf[2][2];
  #pragma unroll
  for (int i = 0; i < 2; ++i)
    #pragma unroll
    for (int ks = 0; ks < 2; ++ks)
      qf[i][ks] = *(const bf16x8*)(qptr + (size_t)(qbase + i * 16 + l16) * 2048 + ks * 32 + quad * 8);

  const u16* kptr = qk + (size_t)(b * 2048) * 2048 + 1024 + h * 64;
  const u16* vptr = vt + (size_t)bh * 131072;

  const int srow = tid >> 3, scol = (tid & 7) * 8;

  f32x4 o[2][4] = {};
  f32x4 lacc[2] = {};
  const short one = (short)0x3F80;  // bf16 1.0
  const bf16x8 ones = {one, one, one, one, one, one, one, one};
  const float c2 = 0.125f * 1.44269504088896340736f;

  bf16x8 k0 = *(const bf16x8*)(kptr + (size_t)srow * 2048 + scol);
  bf16x8 k1 = *(const bf16x8*)(kptr + (size_t)(srow + 32) * 2048 + scol);
  bf16x8 v0 = *(const bf16x8*)(vptr + (size_t)srow * 2048 + scol);
  bf16x8 v1 = *(const bf16x8*)(vptr + (size_t)(srow + 32) * 2048 + scol);

  for (int kv0 = 0; kv0 < 2048; kv0 += 64) {
    __syncthreads();
    *(bf16x8*)&Ks[srow][scol]      = k0;
    *(bf16x8*)&Ks[srow + 32][scol] = k1;
    *(bf16x8*)&Vs[srow][scol]      = v0;
    *(bf16x8*)&Vs[srow + 32][scol] = v1;
    __syncthreads();
    const int kvn = (kv0 + 64) & 2047;
    k0 = *(const bf16x8*)(kptr + (size_t)(kvn + srow) * 2048 + scol);
    k1 = *(const bf16x8*)(kptr + (size_t)(kvn + srow + 32) * 2048 + scol);
    v0 = *(const bf16x8*)(vptr + (size_t)srow * 2048 + kvn + scol);
    v1 = *(const bf16x8*)(vptr + (size_t)(srow + 32) * 2048 + kvn + scol);

    f32x4 s[2][4] = {};
    #pragma unroll
    for (int jj = 0; jj < 4; ++jj) {
      #pragma unroll
      for (int ks = 0; ks < 2; ++ks) {
        bf16x8 kf = *(const bf16x8*)&Ks[jj * 16 + l16][ks * 32 + quad * 8];
        #pragma unroll
        for (int i = 0; i < 2; ++i)
          s[i][jj] = __builtin_amdgcn_mfma_f32_16x16x32_bf16(qf[i][ks], kf, s[i][jj], 0, 0, 0);
      }
    }
    #pragma unroll
    for (int i = 0; i < 2; ++i)
      #pragma unroll
      for (int jj = 0; jj < 4; ++jj)
        #pragma unroll
        for (int r = 0; r < 4; ++r) {
          const float p = __builtin_amdgcn_exp2f(s[i][jj][r] * c2);  // bare v_exp_f32
          union { float f; unsigned u; } vv; vv.f = p;
          Pl[w][i * 16 + quad * 4 + r][jj * 16 + l16] = (u16)((vv.u + 0x8000u) >> 16);
        }
    #pragma unroll
    for (int ks = 0; ks < 2; ++ks) {
      bf16x8 af0 = *(const bf16x8*)&Pl[w][l16][ks * 32 + quad * 8];
      bf16x8 af1 = *(const bf16x8*)&Pl[w][16 + l16][ks * 32 + quad * 8];
      lacc[0] = __builtin_amdgcn_mfma_f32_16x16x32_bf16(af0, ones, lacc[0], 0, 0, 0);
      lacc[1] = __builtin_amdgcn_mfma_f32_16x16x32_bf16(af1, ones, lacc[1], 0, 0, 0);
      #pragma unroll
      for (int j = 0; j < 4; ++j) {
        bf16x8 vf = *(const bf16x8*)&Vs[j * 16 + l16][ks * 32 + quad * 8];
        o[0][j] = __builtin_amdgcn_mfma_f32_16x16x32_bf16(af0, vf, o[0][j], 0, 0, 0);
        o[1][j] = __builtin_amdgcn_mfma_f32_16x16x32_bf16(af1, vf, o[1][j], 0, 0, 0);
      }
    }
  }

  u16* cbase = ctx + (size_t)(b * 2048) * 1024 + h * 64;
  #pragma unroll
  for (int i = 0; i < 2; ++i)
    #pragma unroll
    for (int r = 0; r < 4; ++r) {
      const float inv = 1.0f / lacc[i][r];
      const int q = qbase + i * 16 + quad * 4 + r;
      #pragma unroll
      for (int j = 0; j < 4; ++j)
        cbase[(size_t)q * 1024 + j * 16 + l16] = f2bf(o[i][j][r] * inv);
    }
}

extern "C" void kernel_launch(void* const* d_in, const int* in_sizes, int n_in,
                              void* d_out, int out_size, void* d_ws, size_t ws_size,
                              hipStream_t stream) {
  (void)out_size;
  const float *x = nullptr, *wq = nullptr, *bq = nullptr, *wp = nullptr, *bp = nullptr;
  for (int i = 0; i < n_in; ++i) {
    switch (in_sizes[i]) {
      case 8388608: x  = (const float*)d_in[i]; break;
      case 3145728: wq = (const float*)d_in[i]; break;
      case 3072:    bq = (const float*)d_in[i]; break;
      case 1048576: wp = (const float*)d_in[i]; break;
      case 1024:    bp = (const float*)d_in[i]; break;
      default: break;
    }
  }
  if (!x || !wq || !bq || !wp || !bp) {
    x  = (const float*)d_in[0]; wq = (const float*)d_in[1];
    bq = (const float*)d_in[2]; wp = (const float*)d_in[3];
    bp = (const float*)d_in[4];
  }
  float* out = (float*)d_out;

  const size_t NEED = 75497472;
  if (ws_size < NEED) return;

  char* ws = (char*)d_ws;
  u16* qkb = (u16*)(ws);              // [8192][2048] Q,K
  u16* vt  = (u16*)(ws + 33554432);   // [64][64][2048] V^T
  u16* xbf = (u16*)(ws + 50331648);   // x_bf, then ctx
  u16* wT1 = (u16*)(ws + 67108864);
  u16* wT2 = (u16*)(ws + 73400320);

  convert_x<<<8192, 256, 0, stream>>>(x, xbf);
  transpose_f32_bf16<<<dim3(96, 32), 256, 0, stream>>>(wq, wT1, 1024, 3072);
  transpose_f32_bf16<<<dim3(32, 32), 256, 0, stream>>>(wp, wT2, 1024, 1024);
  gemm1_qkv<<<dim3(64, 24), 256, 0, stream>>>(xbf, wT1, bq, qkb, vt, 1024);
  attn_fused<<<dim3(64, 16), 256, 0, stream>>>(qkb, vt, xbf /*ctx*/);
  gemm2_proj<<<dim3(64, 8), 256, 0, stream>>>(xbf /*ctx*/, wT2, bp, out, 1024);
}

// Round 4
// 280.647 us; speedup vs baseline: 1.5611x; 1.0337x over previous
//
#include <hip/hip_runtime.h>

typedef unsigned short u16;
typedef __attribute__((ext_vector_type(8))) short bf16x8;   // 8 bf16 (4 VGPRs)
typedef __attribute__((ext_vector_type(4))) float f32x4;    // 16x16 MFMA C/D frag
typedef __attribute__((ext_vector_type(16))) float f32x16;  // 32x32 MFMA C/D frag

__device__ __forceinline__ float bf2f(u16 x) {
  union { unsigned u; float f; } v; v.u = ((unsigned)x) << 16; return v.f;
}
__device__ __forceinline__ u16 f2bf(float f) {
  union { float f; unsigned u; } v; v.f = f;
  unsigned r = v.u + 0x7FFFu + ((v.u >> 16) & 1u);  // RNE
  return (u16)(r >> 16);
}
__device__ __forceinline__ float clampf(float v) {
  return fmaxf(fminf(v, 1.0e4f), -1.0e4f);
}
// async global->LDS, 16B per lane; LDS dest = wave-uniform base + lane*16
__device__ __forceinline__ void gll16(const u16* g, u16* l) {
  __builtin_amdgcn_global_load_lds(
      (const __attribute__((address_space(1))) void*)g,
      (__attribute__((address_space(3))) void*)l, 16, 0, 0);
}
// pack two f32 -> one u32 of 2 bf16 (RNE), lo = first arg
__device__ __forceinline__ unsigned cvtpk(float lo, float hi) {
  unsigned r;
  asm("v_cvt_pk_bf16_f32 %0, %1, %2" : "=v"(r) : "v"(lo), "v"(hi));
  return r;
}

// ---------- convert x (f32) -> bf16 ----------
__global__ __launch_bounds__(256) void convert_x(
    const float* __restrict__ x, u16* __restrict__ xbf) {
  const int i0 = (blockIdx.x * 256 + threadIdx.x) * 4;
  const float4 v = *(const float4*)(x + i0);
  xbf[i0 + 0] = f2bf(v.x); xbf[i0 + 1] = f2bf(v.y);
  xbf[i0 + 2] = f2bf(v.z); xbf[i0 + 3] = f2bf(v.w);
}

// ---------- transpose f32 in[R][C] -> bf16 out[C][R] ----------
__global__ __launch_bounds__(256) void transpose_f32_bf16(
    const float* __restrict__ in, u16* __restrict__ out, int R, int C) {
  __shared__ u16 tile[32][33];
  const int bc = blockIdx.x * 32, br = blockIdx.y * 32;
  const int tx = threadIdx.x & 31, ty = threadIdx.x >> 5;
  #pragma unroll
  for (int i = ty; i < 32; i += 8)
    tile[i][tx] = f2bf(in[(size_t)(br + i) * C + bc + tx]);
  __syncthreads();
  #pragma unroll
  for (int i = ty; i < 32; i += 8)
    out[(size_t)(bc + i) * R + br + tx] = tile[tx][i];
}

// ---------- GEMM1: QKV projection, BK=64 dual 32-col LDS (FROZEN R14) ----------
__global__ __launch_bounds__(256) void gemm1_qkv(
    const u16* __restrict__ A, const u16* __restrict__ Bt,
    const float* __restrict__ bias, u16* __restrict__ qk,
    u16* __restrict__ vt, int K) {
  __shared__ u16 As0[128 * 32], As1[128 * 32];
  __shared__ u16 Bs0[128 * 32], Bs1[128 * 32];
  const int tid = threadIdx.x;
  const int m0 = blockIdx.x * 128, n0 = blockIdx.y * 128;
  const int wave = tid >> 6, lane = tid & 63;
  const int quad = lane >> 4, l16 = lane & 15;
  const int wm = (wave >> 1) * 64, wn = (wave & 1) * 64;
  const int sr = (lane >> 2), sp = lane & 3;

  f32x4 acc[4][4] = {};
  const u16* gA = A + (size_t)(m0 + wave * 32 + sr) * K + sp * 8;
  const u16* gB = Bt + (size_t)(n0 + wave * 32 + sr) * K + sp * 8;

  for (int k0 = 0; k0 < K; k0 += 64) {
    #pragma unroll
    for (int t = 0; t < 2; ++t) {
      gll16(gA + (size_t)(t * 16) * K + k0,      &As0[(wave * 32 + t * 16) * 32]);
      gll16(gA + (size_t)(t * 16) * K + k0 + 32, &As1[(wave * 32 + t * 16) * 32]);
      gll16(gB + (size_t)(t * 16) * K + k0,      &Bs0[(wave * 32 + t * 16) * 32]);
      gll16(gB + (size_t)(t * 16) * K + k0 + 32, &Bs1[(wave * 32 + t * 16) * 32]);
    }
    __syncthreads();
    #pragma unroll
    for (int ks = 0; ks < 2; ++ks) {
      const u16* Ah = ks ? As1 : As0;
      const u16* Bh = ks ? Bs1 : Bs0;
      bf16x8 af[4], bfr[4];
      #pragma unroll
      for (int i = 0; i < 4; ++i)
        af[i] = *(const bf16x8*)&Ah[(wm + i * 16 + l16) * 32 + quad * 8];
      #pragma unroll
      for (int j = 0; j < 4; ++j)
        bfr[j] = *(const bf16x8*)&Bh[(wn + j * 16 + l16) * 32 + quad * 8];
      #pragma unroll
      for (int i = 0; i < 4; ++i)
        #pragma unroll
        for (int j = 0; j < 4; ++j)
          acc[i][j] = __builtin_amdgcn_mfma_f32_16x16x32_bf16(af[i], bfr[j], acc[i][j], 0, 0, 0);
    }
    __syncthreads();
  }

  #pragma unroll
  for (int i = 0; i < 4; ++i) {
    const int row = m0 + wm + i * 16 + quad * 4;
    #pragma unroll
    for (int j = 0; j < 4; ++j) {
      const int col = n0 + wn + j * 16 + l16;
      const float bv = bias[col];
      if (col < 2048) {
        #pragma unroll
        for (int r = 0; r < 4; ++r)
          qk[(size_t)(row + r) * 2048 + col] = f2bf(clampf(acc[i][j][r] + bv));
      } else {
        const int d = col & 63;
        const int hh = (col - 2048) >> 6;
        #pragma unroll
        for (int r = 0; r < 4; ++r) {
          const int rr = row + r;
          const int bb = rr >> 11, ss = rr & 2047;
          vt[(size_t)(bb * 16 + hh) * 131072 + d * 2048 + ss] =
              f2bf(clampf(acc[i][j][r] + bv));
        }
      }
    }
  }
}

// ---------- GEMM2: out(f32) = ctx * w_proj^T + bias (FROZEN R14) ----------
__global__ __launch_bounds__(256) void gemm2_proj(
    const u16* __restrict__ A, const u16* __restrict__ Bt,
    const float* __restrict__ bias, float* __restrict__ out, int K) {
  __shared__ u16 As0[128 * 32], As1[128 * 32];
  __shared__ u16 Bs0[128 * 32], Bs1[128 * 32];
  const int tid = threadIdx.x;
  const int m0 = blockIdx.x * 128, n0 = blockIdx.y * 128;
  const int wave = tid >> 6, lane = tid & 63;
  const int quad = lane >> 4, l16 = lane & 15;
  const int wm = (wave >> 1) * 64, wn = (wave & 1) * 64;
  const int sr = (lane >> 2), sp = lane & 3;

  f32x4 acc[4][4] = {};
  const u16* gA = A + (size_t)(m0 + wave * 32 + sr) * K + sp * 8;
  const u16* gB = Bt + (size_t)(n0 + wave * 32 + sr) * K + sp * 8;

  for (int k0 = 0; k0 < K; k0 += 64) {
    #pragma unroll
    for (int t = 0; t < 2; ++t) {
      gll16(gA + (size_t)(t * 16) * K + k0,      &As0[(wave * 32 + t * 16) * 32]);
      gll16(gA + (size_t)(t * 16) * K + k0 + 32, &As1[(wave * 32 + t * 16) * 32]);
      gll16(gB + (size_t)(t * 16) * K + k0,      &Bs0[(wave * 32 + t * 16) * 32]);
      gll16(gB + (size_t)(t * 16) * K + k0 + 32, &Bs1[(wave * 32 + t * 16) * 32]);
    }
    __syncthreads();
    #pragma unroll
    for (int ks = 0; ks < 2; ++ks) {
      const u16* Ah = ks ? As1 : As0;
      const u16* Bh = ks ? Bs1 : Bs0;
      bf16x8 af[4], bfr[4];
      #pragma unroll
      for (int i = 0; i < 4; ++i)
        af[i] = *(const bf16x8*)&Ah[(wm + i * 16 + l16) * 32 + quad * 8];
      #pragma unroll
      for (int j = 0; j < 4; ++j)
        bfr[j] = *(const bf16x8*)&Bh[(wn + j * 16 + l16) * 32 + quad * 8];
      #pragma unroll
      for (int i = 0; i < 4; ++i)
        #pragma unroll
        for (int j = 0; j < 4; ++j)
          acc[i][j] = __builtin_amdgcn_mfma_f32_16x16x32_bf16(af[i], bfr[j], acc[i][j], 0, 0, 0);
    }
    __syncthreads();
  }

  #pragma unroll
  for (int i = 0; i < 4; ++i) {
    const int row = m0 + wm + i * 16 + quad * 4;
    #pragma unroll
    for (int j = 0; j < 4; ++j) {
      const int col = n0 + wn + j * 16 + l16;
      const float bv = bias[col];
      #pragma unroll
      for (int r = 0; r < 4; ++r)
        out[(size_t)(row + r) * 1024 + col] = clampf(acc[i][j][r] + bv);
    }
  }
}

// ---------- fused flash attention, v11: swapped-QK 32x32, P in registers ----
// Post-mortem v7-v10: Pl micro-surgery (stride 72->68, swizzles) moved
// conflicts 10.49M -> 8.39M with zero time gain. The Pl LDS round-trip
// itself (8KB/wave-tile of the 28KB LDS pipe load) + phase serialization is
// the cost. v11 removes P from LDS entirely (guide T12 / m214-v22 recipe):
//   * QK^T swapped via mfma_f32_32x32x16_bf16(K_frag, Q_frag): D col =
//     lane&31 = q, row k = (reg&3)+8*(reg>>2)+4*(lane>>5). Lane owns a full
//     P row for one q.
//   * denominator: in-register adds, halves combined once via ds_bpermute.
//   * PV A-frag built in-register: 4 cvt_pk + 4 ds_bpermute(lane^32) +
//     cndmask per 16-k step (index map verified: word w pairs regs
//     {2w,2w+1} own-half with {2w+4..} cross-half).
//   * K/V in compact [64][64] tiles + v8's PROVEN zero-conflict swizzle
//     key=(row^(row>>2))&7 (32-row fragment reads at stride 72 would be
//     8-way conflicted; swizzle is exact-minimum cycles).
// Geometry FROZEN (R1/R2 lessons): grid (64,16), 128 q-rows/block, 4 waves,
// 2-barrier reg-prefetch staging, LDS padded to EXACTLY 36864 B so
// blocks/CU stays 4 (v9: 5 blocks/CU -> cohort drift -> 5x FETCH).
__device__ __forceinline__ int swz(int row, int col) {
  const int key = (row ^ (row >> 2)) & 7;
  return row * 64 + (((col >> 3) ^ key) << 3) + (col & 7);
}

__global__ __launch_bounds__(256, 4) void attn_fused(
    const u16* __restrict__ qk, const u16* __restrict__ vt,
    u16* __restrict__ ctx) {
  __shared__ u16 Ks[64 * 64];
  __shared__ u16 VsT[64 * 64];
  __shared__ u16 big[10240];  // pad to 36864B total (pins 4 blocks/CU); head used for denom bcast
  const int bh = blockIdx.x, qt = blockIdx.y;
  const int b = bh >> 4, h = bh & 15;
  const int tid = threadIdx.x;
  const int w = tid >> 6, lane = tid & 63;
  const int l31 = lane & 31, hl = lane >> 5;
  const int qbase = qt * 128 + w * 32;
  const int xaddr = (lane ^ 32) << 2;  // ds_bpermute: pull from other half

  // Q fragments (B-operand): lane l31 = q-col, elems d = ds*16 + hl*8 + e
  const u16* qptr = qk + (size_t)(b * 2048) * 2048 + h * 64;
  bf16x8 qf[4];
  #pragma unroll
  for (int ds = 0; ds < 4; ++ds)
    qf[ds] = *(const bf16x8*)(qptr + (size_t)(qbase + l31) * 2048 + ds * 16 + hl * 8);

  const u16* kptr = qk + (size_t)(b * 2048) * 2048 + 1024 + h * 64;
  const u16* vptr = vt + (size_t)bh * 131072;

  const int srow = tid >> 3, scol = (tid & 7) * 8;

  f32x16 o[2] = {};
  float lacc = 0.0f;
  const float c2 = 0.125f * 1.44269504088896340736f;

  bf16x8 k0 = *(const bf16x8*)(kptr + (size_t)srow * 2048 + scol);
  bf16x8 k1 = *(const bf16x8*)(kptr + (size_t)(srow + 32) * 2048 + scol);
  bf16x8 v0 = *(const bf16x8*)(vptr + (size_t)srow * 2048 + scol);
  bf16x8 v1 = *(const bf16x8*)(vptr + (size_t)(srow + 32) * 2048 + scol);

  for (int kv0 = 0; kv0 < 2048; kv0 += 64) {
    __syncthreads();
    *(bf16x8*)&Ks[swz(srow, scol)]       = k0;
    *(bf16x8*)&Ks[swz(srow + 32, scol)]  = k1;
    *(bf16x8*)&VsT[swz(srow, scol)]      = v0;
    *(bf16x8*)&VsT[swz(srow + 32, scol)] = v1;
    __syncthreads();
    const int kvn = (kv0 + 64) & 2047;
    k0 = *(const bf16x8*)(kptr + (size_t)(kvn + srow) * 2048 + scol);
    k1 = *(const bf16x8*)(kptr + (size_t)(kvn + srow + 32) * 2048 + scol);
    v0 = *(const bf16x8*)(vptr + (size_t)srow * 2048 + kvn + scol);
    v1 = *(const bf16x8*)(vptr + (size_t)(srow + 32) * 2048 + kvn + scol);

    #pragma unroll
    for (int kb = 0; kb < 2; ++kb) {
      // QK^T swapped: s^T[k][q], lane col = q, regs = k rows
      f32x16 s = {};
      #pragma unroll
      for (int ds = 0; ds < 4; ++ds) {
        bf16x8 kf = *(const bf16x8*)&Ks[swz(kb * 32 + l31, ds * 16 + hl * 8)];
        s = __builtin_amdgcn_mfma_f32_32x32x16_bf16(kf, qf[ds], s, 0, 0, 0);
      }
      // exp2 in place
      #pragma unroll
      for (int r = 0; r < 16; ++r)
        s[r] = __builtin_amdgcn_exp2f(s[r] * c2);
      // denominator partial (this lane's 16 k's)
      {
        float t0 = (s[0] + s[1]) + (s[2] + s[3]);
        float t1 = (s[4] + s[5]) + (s[6] + s[7]);
        float t2 = (s[8] + s[9]) + (s[10] + s[11]);
        float t3 = (s[12] + s[13]) + (s[14] + s[15]);
        lacc += (t0 + t1) + (t2 + t3);
      }
      // PV: build A-frag in registers per 16-k step, accumulate o
      #pragma unroll
      for (int ksl = 0; ksl < 2; ++ksl) {
        const int r0 = ksl * 8;
        unsigned cA = cvtpk(s[r0 + 0], s[r0 + 1]);
        unsigned cB = cvtpk(s[r0 + 2], s[r0 + 3]);
        unsigned cC = cvtpk(s[r0 + 4], s[r0 + 5]);
        unsigned cD = cvtpk(s[r0 + 6], s[r0 + 7]);
        const unsigned bA = (unsigned)__builtin_amdgcn_ds_bpermute(xaddr, (int)cA);
        const unsigned bB = (unsigned)__builtin_amdgcn_ds_bpermute(xaddr, (int)cB);
        const unsigned bC = (unsigned)__builtin_amdgcn_ds_bpermute(xaddr, (int)cC);
        const unsigned bD = (unsigned)__builtin_amdgcn_ds_bpermute(xaddr, (int)cD);
        union { unsigned u[4]; bf16x8 v; } pf;
        pf.u[0] = hl ? bC : cA;  // e=0,1
        pf.u[1] = hl ? bD : cB;  // e=2,3
        pf.u[2] = hl ? cC : bA;  // e=4,5
        pf.u[3] = hl ? cD : bB;  // e=6,7
        const int kg = kb * 2 + ksl;
        #pragma unroll
        for (int db = 0; db < 2; ++db) {
          bf16x8 vf = *(const bf16x8*)&VsT[swz(db * 32 + l31, kg * 16 + hl * 8)];
          o[db] = __builtin_amdgcn_mfma_f32_32x32x16_bf16(pf.v, vf, o[db], 0, 0, 0);
        }
      }
    }
  }

  // combine lacc halves (lane q and q+32 hold complementary k-partials)
  {
    union { float f; int i; } a, rr;
    a.f = lacc;
    rr.i = __builtin_amdgcn_ds_bpermute(xaddr, a.i);
    lacc = lacc + rr.f;
  }
  // broadcast denom by q via LDS (per-wave region inside pad, no barrier)
  float* dnm = (float*)big;
  if (lane < 32) dnm[w * 32 + lane] = lacc;
  u16* cbase = ctx + (size_t)(b * 2048) * 1024 + h * 64;
  #pragma unroll
  for (int r = 0; r < 16; ++r) {
    const int q0 = (r & 3) + 8 * (r >> 2) + 4 * hl;
    const float inv = 1.0f / dnm[w * 32 + q0];
    const size_t qrow = (size_t)(qbase + q0);
    cbase[qrow * 1024 + l31]      = f2bf(o[0][r] * inv);
    cbase[qrow * 1024 + 32 + l31] = f2bf(o[1][r] * inv);
  }
}

extern "C" void kernel_launch(void* const* d_in, const int* in_sizes, int n_in,
                              void* d_out, int out_size, void* d_ws, size_t ws_size,
                              hipStream_t stream) {
  (void)out_size;
  const float *x = nullptr, *wq = nullptr, *bq = nullptr, *wp = nullptr, *bp = nullptr;
  for (int i = 0; i < n_in; ++i) {
    switch (in_sizes[i]) {
      case 8388608: x  = (const float*)d_in[i]; break;
      case 3145728: wq = (const float*)d_in[i]; break;
      case 3072:    bq = (const float*)d_in[i]; break;
      case 1048576: wp = (const float*)d_in[i]; break;
      case 1024:    bp = (const float*)d_in[i]; break;
      default: break;
    }
  }
  if (!x || !wq || !bq || !wp || !bp) {
    x  = (const float*)d_in[0]; wq = (const float*)d_in[1];
    bq = (const float*)d_in[2]; wp = (const float*)d_in[3];
    bp = (const float*)d_in[4];
  }
  float* out = (float*)d_out;

  const size_t NEED = 75497472;
  if (ws_size < NEED) return;

  char* ws = (char*)d_ws;
  u16* qkb = (u16*)(ws);              // [8192][2048] Q,K
  u16* vt  = (u16*)(ws + 33554432);   // [64][64][2048] V^T
  u16* xbf = (u16*)(ws + 50331648);   // x_bf, then ctx
  u16* wT1 = (u16*)(ws + 67108864);
  u16* wT2 = (u16*)(ws + 73400320);

  convert_x<<<8192, 256, 0, stream>>>(x, xbf);
  transpose_f32_bf16<<<dim3(96, 32), 256, 0, stream>>>(wq, wT1, 1024, 3072);
  transpose_f32_bf16<<<dim3(32, 32), 256, 0, stream>>>(wp, wT2, 1024, 1024);
  gemm1_qkv<<<dim3(64, 24), 256, 0, stream>>>(xbf, wT1, bq, qkb, vt, 1024);
  attn_fused<<<dim3(64, 16), 256, 0, stream>>>(qkb, vt, xbf /*ctx*/);
  gemm2_proj<<<dim3(64, 8), 256, 0, stream>>>(xbf /*ctx*/, wT2, bp, out, 1024);
}

// Round 6
// 280.487 us; speedup vs baseline: 1.5620x; 1.0006x over previous
//
#include <hip/hip_runtime.h>

typedef unsigned short u16;
typedef __attribute__((ext_vector_type(8))) short bf16x8;   // 8 bf16 (4 VGPRs)
typedef __attribute__((ext_vector_type(4))) float f32x4;    // 16x16 MFMA C/D frag
typedef __attribute__((ext_vector_type(16))) float f32x16;  // 32x32 MFMA C/D frag

__device__ __forceinline__ float bf2f(u16 x) {
  union { unsigned u; float f; } v; v.u = ((unsigned)x) << 16; return v.f;
}
__device__ __forceinline__ u16 f2bf(float f) {
  union { float f; unsigned u; } v; v.f = f;
  unsigned r = v.u + 0x7FFFu + ((v.u >> 16) & 1u);  // RNE
  return (u16)(r >> 16);
}
__device__ __forceinline__ float clampf(float v) {
  return fmaxf(fminf(v, 1.0e4f), -1.0e4f);
}
// async global->LDS, 16B per lane; LDS dest = wave-uniform base + lane*16
__device__ __forceinline__ void gll16(const u16* g, u16* l) {
  __builtin_amdgcn_global_load_lds(
      (const __attribute__((address_space(1))) void*)g,
      (__attribute__((address_space(3))) void*)l, 16, 0, 0);
}
// pack two f32 -> one u32 of 2 bf16 (RNE), lo = first arg
__device__ __forceinline__ unsigned cvtpk(float lo, float hi) {
  unsigned r;
  asm("v_cvt_pk_bf16_f32 %0, %1, %2" : "=v"(r) : "v"(lo), "v"(hi));
  return r;
}

// ---------- convert x (f32) -> bf16 ----------
__global__ __launch_bounds__(256) void convert_x(
    const float* __restrict__ x, u16* __restrict__ xbf) {
  const int i0 = (blockIdx.x * 256 + threadIdx.x) * 4;
  const float4 v = *(const float4*)(x + i0);
  xbf[i0 + 0] = f2bf(v.x); xbf[i0 + 1] = f2bf(v.y);
  xbf[i0 + 2] = f2bf(v.z); xbf[i0 + 3] = f2bf(v.w);
}

// ---------- transpose f32 in[R][C] -> bf16 out[C][R] ----------
__global__ __launch_bounds__(256) void transpose_f32_bf16(
    const float* __restrict__ in, u16* __restrict__ out, int R, int C) {
  __shared__ u16 tile[32][33];
  const int bc = blockIdx.x * 32, br = blockIdx.y * 32;
  const int tx = threadIdx.x & 31, ty = threadIdx.x >> 5;
  #pragma unroll
  for (int i = ty; i < 32; i += 8)
    tile[i][tx] = f2bf(in[(size_t)(br + i) * C + bc + tx]);
  __syncthreads();
  #pragma unroll
  for (int i = ty; i < 32; i += 8)
    out[(size_t)(bc + i) * R + br + tx] = tile[tx][i];
}

// ---------- GEMM1: QKV projection, BK=64 dual 32-col LDS (FROZEN R14) ----------
__global__ __launch_bounds__(256) void gemm1_qkv(
    const u16* __restrict__ A, const u16* __restrict__ Bt,
    const float* __restrict__ bias, u16* __restrict__ qk,
    u16* __restrict__ vt, int K) {
  __shared__ u16 As0[128 * 32], As1[128 * 32];
  __shared__ u16 Bs0[128 * 32], Bs1[128 * 32];
  const int tid = threadIdx.x;
  const int m0 = blockIdx.x * 128, n0 = blockIdx.y * 128;
  const int wave = tid >> 6, lane = tid & 63;
  const int quad = lane >> 4, l16 = lane & 15;
  const int wm = (wave >> 1) * 64, wn = (wave & 1) * 64;
  const int sr = (lane >> 2), sp = lane & 3;

  f32x4 acc[4][4] = {};
  const u16* gA = A + (size_t)(m0 + wave * 32 + sr) * K + sp * 8;
  const u16* gB = Bt + (size_t)(n0 + wave * 32 + sr) * K + sp * 8;

  for (int k0 = 0; k0 < K; k0 += 64) {
    #pragma unroll
    for (int t = 0; t < 2; ++t) {
      gll16(gA + (size_t)(t * 16) * K + k0,      &As0[(wave * 32 + t * 16) * 32]);
      gll16(gA + (size_t)(t * 16) * K + k0 + 32, &As1[(wave * 32 + t * 16) * 32]);
      gll16(gB + (size_t)(t * 16) * K + k0,      &Bs0[(wave * 32 + t * 16) * 32]);
      gll16(gB + (size_t)(t * 16) * K + k0 + 32, &Bs1[(wave * 32 + t * 16) * 32]);
    }
    __syncthreads();
    #pragma unroll
    for (int ks = 0; ks < 2; ++ks) {
      const u16* Ah = ks ? As1 : As0;
      const u16* Bh = ks ? Bs1 : Bs0;
      bf16x8 af[4], bfr[4];
      #pragma unroll
      for (int i = 0; i < 4; ++i)
        af[i] = *(const bf16x8*)&Ah[(wm + i * 16 + l16) * 32 + quad * 8];
      #pragma unroll
      for (int j = 0; j < 4; ++j)
        bfr[j] = *(const bf16x8*)&Bh[(wn + j * 16 + l16) * 32 + quad * 8];
      #pragma unroll
      for (int i = 0; i < 4; ++i)
        #pragma unroll
        for (int j = 0; j < 4; ++j)
          acc[i][j] = __builtin_amdgcn_mfma_f32_16x16x32_bf16(af[i], bfr[j], acc[i][j], 0, 0, 0);
    }
    __syncthreads();
  }

  #pragma unroll
  for (int i = 0; i < 4; ++i) {
    const int row = m0 + wm + i * 16 + quad * 4;
    #pragma unroll
    for (int j = 0; j < 4; ++j) {
      const int col = n0 + wn + j * 16 + l16;
      const float bv = bias[col];
      if (col < 2048) {
        #pragma unroll
        for (int r = 0; r < 4; ++r)
          qk[(size_t)(row + r) * 2048 + col] = f2bf(clampf(acc[i][j][r] + bv));
      } else {
        const int d = col & 63;
        const int hh = (col - 2048) >> 6;
        #pragma unroll
        for (int r = 0; r < 4; ++r) {
          const int rr = row + r;
          const int bb = rr >> 11, ss = rr & 2047;
          vt[(size_t)(bb * 16 + hh) * 131072 + d * 2048 + ss] =
              f2bf(clampf(acc[i][j][r] + bv));
        }
      }
    }
  }
}

// ---------- GEMM2: out(f32) = ctx * w_proj^T + bias (FROZEN R14) ----------
__global__ __launch_bounds__(256) void gemm2_proj(
    const u16* __restrict__ A, const u16* __restrict__ Bt,
    const float* __restrict__ bias, float* __restrict__ out, int K) {
  __shared__ u16 As0[128 * 32], As1[128 * 32];
  __shared__ u16 Bs0[128 * 32], Bs1[128 * 32];
  const int tid = threadIdx.x;
  const int m0 = blockIdx.x * 128, n0 = blockIdx.y * 128;
  const int wave = tid >> 6, lane = tid & 63;
  const int quad = lane >> 4, l16 = lane & 15;
  const int wm = (wave >> 1) * 64, wn = (wave & 1) * 64;
  const int sr = (lane >> 2), sp = lane & 3;

  f32x4 acc[4][4] = {};
  const u16* gA = A + (size_t)(m0 + wave * 32 + sr) * K + sp * 8;
  const u16* gB = Bt + (size_t)(n0 + wave * 32 + sr) * K + sp * 8;

  for (int k0 = 0; k0 < K; k0 += 64) {
    #pragma unroll
    for (int t = 0; t < 2; ++t) {
      gll16(gA + (size_t)(t * 16) * K + k0,      &As0[(wave * 32 + t * 16) * 32]);
      gll16(gA + (size_t)(t * 16) * K + k0 + 32, &As1[(wave * 32 + t * 16) * 32]);
      gll16(gB + (size_t)(t * 16) * K + k0,      &Bs0[(wave * 32 + t * 16) * 32]);
      gll16(gB + (size_t)(t * 16) * K + k0 + 32, &Bs1[(wave * 32 + t * 16) * 32]);
    }
    __syncthreads();
    #pragma unroll
    for (int ks = 0; ks < 2; ++ks) {
      const u16* Ah = ks ? As1 : As0;
      const u16* Bh = ks ? Bs1 : Bs0;
      bf16x8 af[4], bfr[4];
      #pragma unroll
      for (int i = 0; i < 4; ++i)
        af[i] = *(const bf16x8*)&Ah[(wm + i * 16 + l16) * 32 + quad * 8];
      #pragma unroll
      for (int j = 0; j < 4; ++j)
        bfr[j] = *(const bf16x8*)&Bh[(wn + j * 16 + l16) * 32 + quad * 8];
      #pragma unroll
      for (int i = 0; i < 4; ++i)
        #pragma unroll
        for (int j = 0; j < 4; ++j)
          acc[i][j] = __builtin_amdgcn_mfma_f32_16x16x32_bf16(af[i], bfr[j], acc[i][j], 0, 0, 0);
    }
    __syncthreads();
  }

  #pragma unroll
  for (int i = 0; i < 4; ++i) {
    const int row = m0 + wm + i * 16 + quad * 4;
    #pragma unroll
    for (int j = 0; j < 4; ++j) {
      const int col = n0 + wn + j * 16 + l16;
      const float bv = bias[col];
      #pragma unroll
      for (int r = 0; r < 4; ++r)
        out[(size_t)(row + r) * 1024 + col] = clampf(acc[i][j][r] + bv);
    }
  }
}

// ---------- fused flash attention, v13 ----------
// Post-mortem v12: FAILED (absmax 0.097, stale-tile-sized error). v12
// bundled two edits: (1) hoisted swizzle offsets (value-identical refactor)
// and (2) single-barrier double-buffer (new sync structure). Violation of
// two-lane discipline; the race is in (2) -- likely the WAR between staging
// ds_writes (reading prefetch regs) and the adjacent global loads
// overwriting those regs, which v11's second __syncthreads incidentally
// fenced. BISECT: v13 = v11's PROVEN schedule (two barriers, single K/V
// buffer, prefetch-distance-1) + ONLY edit (1).
// v11 baseline: 99.4us, conflicts 0, MFMA-busy 29.8us == computed floor,
// VALU 44% = binding pipe, VGPR 60 (compiler remats 24 swz() addrs/tile).
// Geometry frozen: grid (64,16), LDS exactly 36864B -> 4 blocks/CU.
__device__ __forceinline__ int swz(int row, int col) {
  const int key = (row ^ (row >> 2)) & 7;
  return row * 64 + (((col >> 3) ^ key) << 3) + (col & 7);
}

__global__ __launch_bounds__(256, 4) void attn_fused(
    const u16* __restrict__ qk, const u16* __restrict__ vt,
    u16* __restrict__ ctx) {
  __shared__ u16 Ks[64 * 64];
  __shared__ u16 VsT[64 * 64];
  __shared__ u16 big[10240];  // pad to 36864B total (pins 4 blocks/CU); head used for denom bcast
  const int bh = blockIdx.x, qt = blockIdx.y;
  const int b = bh >> 4, h = bh & 15;
  const int tid = threadIdx.x;
  const int w = tid >> 6, lane = tid & 63;
  const int l31 = lane & 31, hl = lane >> 5;
  const int qbase = qt * 128 + w * 32;
  const int xaddr = (lane ^ 32) << 2;  // ds_bpermute: pull from other half

  // Q fragments (B-operand): lane l31 = q-col, elems d = ds*16 + hl*8 + e
  const u16* qptr = qk + (size_t)(b * 2048) * 2048 + h * 64;
  bf16x8 qf[4];
  #pragma unroll
  for (int ds = 0; ds < 4; ++ds)
    qf[ds] = *(const bf16x8*)(qptr + (size_t)(qbase + l31) * 2048 + ds * 16 + hl * 8);

  const u16* kptr = qk + (size_t)(b * 2048) * 2048 + 1024 + h * 64;
  const u16* vptr = vt + (size_t)bh * 131072;

  const int srow = tid >> 3, scol = (tid & 7) * 8;

  // loop-invariant LDS offsets (register-resident; unroll-constant indexed)
  const int st0 = swz(srow, scol);
  const int st1 = swz(srow + 32, scol);
  int off[2][4];
  #pragma unroll
  for (int a = 0; a < 2; ++a)
    #pragma unroll
    for (int d = 0; d < 4; ++d)
      off[a][d] = swz(a * 32 + l31, d * 16 + hl * 8);

  // loop-invariant global bases
  const u16* kB0 = kptr + (size_t)srow * 2048 + scol;
  const u16* kB1 = kptr + (size_t)(srow + 32) * 2048 + scol;
  const u16* vB0 = vptr + (size_t)srow * 2048 + scol;
  const u16* vB1 = vptr + (size_t)(srow + 32) * 2048 + scol;

  f32x16 o[2] = {};
  float lacc = 0.0f;
  const float c2 = 0.125f * 1.44269504088896340736f;

  bf16x8 k0 = *(const bf16x8*)kB0;
  bf16x8 k1 = *(const bf16x8*)kB1;
  bf16x8 v0 = *(const bf16x8*)vB0;
  bf16x8 v1 = *(const bf16x8*)vB1;

  for (int kv0 = 0; kv0 < 2048; kv0 += 64) {
    __syncthreads();
    *(bf16x8*)&Ks[st0]  = k0;
    *(bf16x8*)&Ks[st1]  = k1;
    *(bf16x8*)&VsT[st0] = v0;
    *(bf16x8*)&VsT[st1] = v1;
    __syncthreads();
    const int kvn = (kv0 + 64) & 2047;
    k0 = *(const bf16x8*)(kB0 + (size_t)kvn * 2048);
    k1 = *(const bf16x8*)(kB1 + (size_t)kvn * 2048);
    v0 = *(const bf16x8*)(vB0 + kvn);
    v1 = *(const bf16x8*)(vB1 + kvn);

    #pragma unroll
    for (int kb = 0; kb < 2; ++kb) {
      // QK^T swapped: s^T[k][q], lane col = q, regs = k rows
      f32x16 s = {};
      #pragma unroll
      for (int ds = 0; ds < 4; ++ds) {
        bf16x8 kf = *(const bf16x8*)&Ks[off[kb][ds]];
        s = __builtin_amdgcn_mfma_f32_32x32x16_bf16(kf, qf[ds], s, 0, 0, 0);
      }
      // exp2 in place
      #pragma unroll
      for (int r = 0; r < 16; ++r)
        s[r] = __builtin_amdgcn_exp2f(s[r] * c2);
      // denominator partial (this lane's 16 k's)
      {
        float t0 = (s[0] + s[1]) + (s[2] + s[3]);
        float t1 = (s[4] + s[5]) + (s[6] + s[7]);
        float t2 = (s[8] + s[9]) + (s[10] + s[11]);
        float t3 = (s[12] + s[13]) + (s[14] + s[15]);
        lacc += (t0 + t1) + (t2 + t3);
      }
      // PV: build A-frag in registers per 16-k step, accumulate o
      #pragma unroll
      for (int ksl = 0; ksl < 2; ++ksl) {
        const int r0 = ksl * 8;
        unsigned cA = cvtpk(s[r0 + 0], s[r0 + 1]);
        unsigned cB = cvtpk(s[r0 + 2], s[r0 + 3]);
        unsigned cC = cvtpk(s[r0 + 4], s[r0 + 5]);
        unsigned cD = cvtpk(s[r0 + 6], s[r0 + 7]);
        const unsigned bA = (unsigned)__builtin_amdgcn_ds_bpermute(xaddr, (int)cA);
        const unsigned bB = (unsigned)__builtin_amdgcn_ds_bpermute(xaddr, (int)cB);
        const unsigned bC = (unsigned)__builtin_amdgcn_ds_bpermute(xaddr, (int)cC);
        const unsigned bD = (unsigned)__builtin_amdgcn_ds_bpermute(xaddr, (int)cD);
        union { unsigned u[4]; bf16x8 v; } pf;
        pf.u[0] = hl ? bC : cA;  // e=0,1
        pf.u[1] = hl ? bD : cB;  // e=2,3
        pf.u[2] = hl ? cC : bA;  // e=4,5
        pf.u[3] = hl ? cD : bB;  // e=6,7
        const int kg = kb * 2 + ksl;
        #pragma unroll
        for (int db = 0; db < 2; ++db) {
          bf16x8 vf = *(const bf16x8*)&VsT[off[db][kg]];
          o[db] = __builtin_amdgcn_mfma_f32_32x32x16_bf16(pf.v, vf, o[db], 0, 0, 0);
        }
      }
    }
  }

  // combine lacc halves (lane q and q+32 hold complementary k-partials)
  {
    union { float f; int i; } a, rr;
    a.f = lacc;
    rr.i = __builtin_amdgcn_ds_bpermute(xaddr, a.i);
    lacc = lacc + rr.f;
  }
  // broadcast denom by q via LDS (per-wave region, no barrier needed)
  float* dnm = (float*)big;
  if (lane < 32) dnm[w * 32 + lane] = lacc;
  u16* cbase = ctx + (size_t)(b * 2048) * 1024 + h * 64;
  #pragma unroll
  for (int r = 0; r < 16; ++r) {
    const int q0 = (r & 3) + 8 * (r >> 2) + 4 * hl;
    const float inv = 1.0f / dnm[w * 32 + q0];
    const size_t qrow = (size_t)(qbase + q0);
    cbase[qrow * 1024 + l31]      = f2bf(o[0][r] * inv);
    cbase[qrow * 1024 + 32 + l31] = f2bf(o[1][r] * inv);
  }
}

extern "C" void kernel_launch(void* const* d_in, const int* in_sizes, int n_in,
                              void* d_out, int out_size, void* d_ws, size_t ws_size,
                              hipStream_t stream) {
  (void)out_size;
  const float *x = nullptr, *wq = nullptr, *bq = nullptr, *wp = nullptr, *bp = nullptr;
  for (int i = 0; i < n_in; ++i) {
    switch (in_sizes[i]) {
      case 8388608: x  = (const float*)d_in[i]; break;
      case 3145728: wq = (const float*)d_in[i]; break;
      case 3072:    bq = (const float*)d_in[i]; break;
      case 1048576: wp = (const float*)d_in[i]; break;
      case 1024:    bp = (const float*)d_in[i]; break;
      default: break;
    }
  }
  if (!x || !wq || !bq || !wp || !bp) {
    x  = (const float*)d_in[0]; wq = (const float*)d_in[1];
    bq = (const float*)d_in[2]; wp = (const float*)d_in[3];
    bp = (const float*)d_in[4];
  }
  float* out = (float*)d_out;

  const size_t NEED = 75497472;
  if (ws_size < NEED) return;

  char* ws = (char*)d_ws;
  u16* qkb = (u16*)(ws);              // [8192][2048] Q,K
  u16* vt  = (u16*)(ws + 33554432);   // [64][64][2048] V^T
  u16* xbf = (u16*)(ws + 50331648);   // x_bf, then ctx
  u16* wT1 = (u16*)(ws + 67108864);
  u16* wT2 = (u16*)(ws + 73400320);

  convert_x<<<8192, 256, 0, stream>>>(x, xbf);
  transpose_f32_bf16<<<dim3(96, 32), 256, 0, stream>>>(wq, wT1, 1024, 3072);
  transpose_f32_bf16<<<dim3(32, 32), 256, 0, stream>>>(wp, wT2, 1024, 1024);
  gemm1_qkv<<<dim3(64, 24), 256, 0, stream>>>(xbf, wT1, bq, qkb, vt, 1024);
  attn_fused<<<dim3(64, 16), 256, 0, stream>>>(qkb, vt, xbf /*ctx*/);
  gemm2_proj<<<dim3(64, 8), 256, 0, stream>>>(xbf /*ctx*/, wT2, bp, out, 1024);
}